// Round 1
// 330.870 us; speedup vs baseline: 1.0309x; 1.0309x over previous
//
#include <hip/hip_runtime.h>
#include <hip/hip_bf16.h>
#include <stdint.h>

typedef __bf16 bh;
typedef __bf16 bf16x8 __attribute__((ext_vector_type(8)));
typedef float f32x4 __attribute__((ext_vector_type(4)));
typedef unsigned int u32;

#define B_  32
#define S_  512
#define R_  196
#define H_  1024
#define BH  (B_ * H_)

// ---------------------------------------------------------------- helpers

__device__ __forceinline__ float fast_tanh(float x) {
  x = fminf(10.f, fmaxf(-10.f, x));
  float e = __expf(2.f * x);
  return (e - 1.f) / (e + 1.f);
}

__device__ __forceinline__ bf16x8 cvt8(const float4 a, const float4 b) {
  bf16x8 r;
  r[0] = (bh)a.x; r[1] = (bh)a.y; r[2] = (bh)a.z; r[3] = (bh)a.w;
  r[4] = (bh)b.x; r[5] = (bh)b.y; r[6] = (bh)b.z; r[7] = (bh)b.w;
  return r;
}

// async global->LDS, 16B per lane. LDS dest is wave-uniform base + lane*16;
// global src is per-lane. size MUST be a literal.
__device__ __forceinline__ void gload_lds16(const bh* g, bh* l) {
  __builtin_amdgcn_global_load_lds(
      (__attribute__((address_space(1))) void*)g,
      (__attribute__((address_space(3))) void*)l,
      16, 0, 0);
}

// ---------------------------------------------------------------- kernel 0
// One-shot fp32 -> bf16 conversion of dns, img, Wd2, Wi1 (row-major kept).
// 8 elems per thread per iter (2 float4 loads -> one 16B bf16x8 store).
#define G_DNS 2097152   // 32*512*1024/8
#define G_IMG 802816    // 32*196*1024/8
#define G_W   131072    // 1024*1024/8
#define G_TOT (G_DNS + G_IMG + 2 * G_W)

__global__ __launch_bounds__(256)
void convert_kernel(const float* __restrict__ dns, const float* __restrict__ img,
                    const float* __restrict__ Wd2, const float* __restrict__ Wi1,
                    bh* __restrict__ dnsB, bh* __restrict__ imgB,
                    bh* __restrict__ wd2B, bh* __restrict__ wi1B) {
  for (int g = blockIdx.x * 256 + threadIdx.x; g < G_TOT; g += gridDim.x * 256) {
    const float* src; bh* dst; int off;
    if (g < G_DNS)                  { src = dns; dst = dnsB; off = g; }
    else if (g < G_DNS + G_IMG)     { src = img; dst = imgB; off = g - G_DNS; }
    else if (g < G_DNS + G_IMG + G_W) { src = Wd2; dst = wd2B; off = g - G_DNS - G_IMG; }
    else                            { src = Wi1; dst = wi1B; off = g - G_DNS - G_IMG - G_W; }
    float4 a = ((const float4*)src)[(size_t)off * 2];
    float4 b = ((const float4*)src)[(size_t)off * 2 + 1];
    ((bf16x8*)dst)[off] = cvt8(a, b);
  }
}

// ---------------------------------------------------------------- kernel 1
// Fused GEMM + tanh + weighted-reduce on pre-converted bf16 inputs.
// m97 structure: 128x128 tile, BK=32, 4 waves of 64x64, 16x16x32 bf16 MFMA,
// global_load_lds width-16 staging (linear LDS layout, lane-order exact).
// grid: x = n-tile (8, fastest -> A-tile shared by 8 consecutive blocks),
//       y = m-tile (128 dns + 49 img).
//   sPart[m*8 + ny] = sum_{o in n-block ny} w[o] * tanh( sum_h X[m,h]*W[o,h] )

__global__ __launch_bounds__(256, 3)
void score_gemm_kernel(const bh* __restrict__ dnsB, const bh* __restrict__ imgB,
                       const bh* __restrict__ Wd2B, const bh* __restrict__ Wi1B,
                       const float* __restrict__ watt1, const float* __restrict__ watt2,
                       float* __restrict__ sPartD, float* __restrict__ sPartB) {
  __shared__ __align__(16) bh As[128 * 32];
  __shared__ __align__(16) bh Bs[128 * 32];
  __shared__ float sred[128];

  const int tid = threadIdx.x;
  const int wave = tid >> 6, lane = tid & 63;
  const int ny = blockIdx.x, my = blockIdx.y;

  const bh* X; const bh* W; const float* w; float* sp; int m0;
  if (my < 128) { X = dnsB; W = Wd2B; w = watt2 + H_; sp = sPartD; m0 = my * 128; }
  else          { X = imgB; W = Wi1B; w = watt1 + H_; sp = sPartB; m0 = (my - 128) * 128; }
  const int n0 = ny * 128;

  // staging: wave w covers rows w*32 .. w*32+31 via 2 instrs of 16 rows.
  // lane l -> row += l>>2, byte col (l&3)*16 (8 bf16). LDS row = 32 bf16 = 64B,
  // so lane l writes base + 16*l exactly (linear, no padding).
  const int srow = wave * 32 + (lane >> 2);
  const int sseg = (lane & 3) * 8;
  const bh* Ag = X + ((size_t)(m0 + srow) * H_ + sseg);
  const bh* Bg = W + ((size_t)(n0 + srow) * H_ + sseg);
  bh* Al = As + (wave * 32) * 32;   // wave-uniform
  bh* Bl = Bs + (wave * 32) * 32;

  const int wm = wave >> 1, wn = wave & 1;
  const int col = lane & 15, quad = lane >> 4;

  f32x4 acc[4][4] = {};

  for (int kt = 0; kt < 32; ++kt) {
    if (kt) __syncthreads();               // previous tile fully consumed
    const int ko = kt * 32;
    gload_lds16(Ag + ko,              Al);
    gload_lds16(Ag + ko + 16 * H_,    Al + 16 * 32);
    gload_lds16(Bg + ko,              Bl);
    gload_lds16(Bg + ko + 16 * H_,    Bl + 16 * 32);
    __syncthreads();                       // compiler drains vmcnt(0) here

    bf16x8 af[4], bfr[4];
#pragma unroll
    for (int mi = 0; mi < 4; ++mi)
      af[mi] = *(const bf16x8*)(As + (wm * 64 + mi * 16 + col) * 32 + quad * 8);
#pragma unroll
    for (int ni = 0; ni < 4; ++ni)
      bfr[ni] = *(const bf16x8*)(Bs + (wn * 64 + ni * 16 + col) * 32 + quad * 8);

#pragma unroll
    for (int mi = 0; mi < 4; ++mi)
#pragma unroll
      for (int ni = 0; ni < 4; ++ni)
        acc[mi][ni] = __builtin_amdgcn_mfma_f32_16x16x32_bf16(af[mi], bfr[ni], acc[mi][ni], 0, 0, 0);
  }

  // epilogue: tanh -> *w[o] -> reduce over this block's 128 o-columns.
  // C/D layout (verified m89): col = lane&15, row = quad*4 + reg.
  float wv[4];
#pragma unroll
  for (int ni = 0; ni < 4; ++ni) wv[ni] = w[n0 + wn * 64 + ni * 16 + col];

  float ppv[4][4];
#pragma unroll
  for (int mi = 0; mi < 4; ++mi) {
#pragma unroll
    for (int reg = 0; reg < 4; ++reg) {
      float pp = 0.f;
#pragma unroll
      for (int ni = 0; ni < 4; ++ni) pp += fast_tanh(acc[mi][ni][reg]) * wv[ni];
      pp += __shfl_xor(pp, 1);
      pp += __shfl_xor(pp, 2);
      pp += __shfl_xor(pp, 4);
      pp += __shfl_xor(pp, 8);
      ppv[mi][reg] = pp;   // valid where col==0
    }
  }

  if (wn == 0 && col == 0) {
#pragma unroll
    for (int mi = 0; mi < 4; ++mi)
#pragma unroll
      for (int reg = 0; reg < 4; ++reg)
        sred[wm * 64 + mi * 16 + quad * 4 + reg] = ppv[mi][reg];
  }
  __syncthreads();
  if (wn == 1 && col == 0) {
#pragma unroll
    for (int mi = 0; mi < 4; ++mi)
#pragma unroll
      for (int reg = 0; reg < 4; ++reg) {
        int ml = wm * 64 + mi * 16 + quad * 4 + reg;
        sp[(size_t)(m0 + ml) * 8 + ny] = sred[ml] + ppv[mi][reg];
      }
  }
}

// ---------------------------------------------------------------- kernel 2
// Sum 8 partials -> logits -> per-batch softmax.
__global__ __launch_bounds__(512)
void softmax_kernel(const float* __restrict__ sPartD, const float* __restrict__ sPartB,
                    float* __restrict__ q, float* __restrict__ p) {
  __shared__ float red[8];
  const int b = blockIdx.x, tid = threadIdx.x;
  const int wave = tid >> 6, lane = tid & 63;

  {  // dns side, 512 logits
    const float4* p4 = (const float4*)(sPartD + (size_t)(b * S_ + tid) * 8);
    float4 x0 = p4[0], x1 = p4[1];
    float x = x0.x + x0.y + x0.z + x0.w + x1.x + x1.y + x1.z + x1.w;
    float wm = x;
#pragma unroll
    for (int msk = 32; msk; msk >>= 1) wm = fmaxf(wm, __shfl_xor(wm, msk));
    if (!lane) red[wave] = wm;
    __syncthreads();
    float bm = red[0];
#pragma unroll
    for (int i = 1; i < 8; ++i) bm = fmaxf(bm, red[i]);
    __syncthreads();
    float e = __expf(x - bm);
    float ws = e;
#pragma unroll
    for (int msk = 32; msk; msk >>= 1) ws += __shfl_xor(ws, msk);
    if (!lane) red[wave] = ws;
    __syncthreads();
    float bs = 0.f;
#pragma unroll
    for (int i = 0; i < 8; ++i) bs += red[i];
    q[b * S_ + tid] = e / bs;
    __syncthreads();
  }
  {  // img side, 196 logits
    float x = -3.0e38f;
    if (tid < R_) {
      const float4* p4 = (const float4*)(sPartB + (size_t)(b * R_ + tid) * 8);
      float4 x0 = p4[0], x1 = p4[1];
      x = x0.x + x0.y + x0.z + x0.w + x1.x + x1.y + x1.z + x1.w;
    }
    float wm = x;
#pragma unroll
    for (int msk = 32; msk; msk >>= 1) wm = fmaxf(wm, __shfl_xor(wm, msk));
    if (!lane) red[wave] = wm;
    __syncthreads();
    float bm = red[0];
#pragma unroll
    for (int i = 1; i < 8; ++i) bm = fmaxf(bm, red[i]);
    __syncthreads();
    float e = (tid < R_) ? __expf(x - bm) : 0.f;
    float ws = e;
#pragma unroll
    for (int msk = 32; msk; msk >>= 1) ws += __shfl_xor(ws, msk);
    if (!lane) red[wave] = ws;
    __syncthreads();
    float bs = 0.f;
#pragma unroll
    for (int i = 0; i < 8; ++i) bs += red[i];
    if (tid < R_) p[b * R_ + tid] = e / bs;
  }
}

// ---------------------------------------------------------------- kernel 3
// Weighted sums, per-j-chunk partials (no atomics), FP32 math. Compile-time
// trip counts (32 / 49) so the load loop fully unrolls (deep MLP).
//   uPart[c*BH + b*H + h] = sum_{j in chunk c} q[b,j]*dns[b,j,h]   c=0..15 (32 j)
//   vPart[c*BH + b*H + h] = sum_{r in chunk c} p[b,r]*img[b,r,h]   c=0..3  (49 r)
__global__ __launch_bounds__(256)
void wsum_kernel(const float* __restrict__ dns, const float* __restrict__ img,
                 const float* __restrict__ q, const float* __restrict__ p,
                 float* __restrict__ uPart, float* __restrict__ vPart) {
  __shared__ float qs[64];
  const int b = blockIdx.x, tid = threadIdx.x, zc = blockIdx.y;
  const int h = tid * 4;
  float4 a = {0.f, 0.f, 0.f, 0.f};
  if (zc < 16) {
    const int j0 = zc * 32;
    if (tid < 32) qs[tid] = q[b * S_ + j0 + tid];
    __syncthreads();
    const float* Xb = dns + ((size_t)(b * S_ + j0) * H_ + h);
#pragma unroll
    for (int jj = 0; jj < 32; ++jj) {
      float4 xv = *(const float4*)(Xb + (size_t)jj * H_);
      float qv = qs[jj];
      a.x += qv * xv.x; a.y += qv * xv.y; a.z += qv * xv.z; a.w += qv * xv.w;
    }
    *(float4*)(uPart + (size_t)zc * BH + (size_t)b * H_ + h) = a;
  } else {
    const int j0 = (zc - 16) * 49;
    if (tid < 49) qs[tid] = p[b * R_ + j0 + tid];
    __syncthreads();
    const float* Xb = img + ((size_t)(b * R_ + j0) * H_ + h);
#pragma unroll
    for (int jj = 0; jj < 49; ++jj) {
      float4 xv = *(const float4*)(Xb + (size_t)jj * H_);
      float qv = qs[jj];
      a.x += qv * xv.x; a.y += qv * xv.y; a.z += qv * xv.z; a.w += qv * xv.w;
    }
    *(float4*)(vPart + (size_t)(zc - 16) * BH + (size_t)b * H_ + h) = a;
  }
}

// ---------------------------------------------------------------- kernel 3b
// Combine partials: u[b,h] = sum_{c<16} uPart[c], v[b,h] = sum_{c<4} vPart[c].
__global__ __launch_bounds__(256)
void combine_kernel(const float* __restrict__ uPart, const float* __restrict__ vPart,
                    float* __restrict__ u, float* __restrict__ v) {
  const int b = blockIdx.x, tid = threadIdx.x;
  const int i = b * 256 + tid;   // float4 index into (B,H)
  float4 a = {0.f, 0.f, 0.f, 0.f};
#pragma unroll
  for (int c = 0; c < 16; ++c) {
    float4 s = ((const float4*)(uPart + (size_t)c * BH))[i];
    a.x += s.x; a.y += s.y; a.z += s.z; a.w += s.w;
  }
  ((float4*)u)[i] = a;
  float4 cacc = {0.f, 0.f, 0.f, 0.f};
#pragma unroll
  for (int c = 0; c < 4; ++c) {
    float4 s = ((const float4*)(vPart + (size_t)c * BH))[i];
    cacc.x += s.x; cacc.y += s.y; cacc.z += s.z; cacc.w += s.w;
  }
  ((float4*)v)[i] = cacc;
}

// ---------------------------------------------------------------- kernel 4
// Broadcast write, FP32 OUTPUT: out0[b,s,:] = u[b,:], out1[b,s,:] = v[b,:].
__global__ __launch_bounds__(256)
void bcast_kernel(const float* __restrict__ u, const float* __restrict__ v,
                  float* __restrict__ out) {
  const int PER4 = B_ * S_ * H_ / 4;              // 4,194,304
  const int t = blockIdx.x * 256 + threadIdx.x;   // 0 .. 2*PER4-1
  const int which = (t >= PER4);
  const int r = t - which * PER4;
  const int b = r >> 17;        // S*H/4 = 131072 float4 per batch
  const int h4 = r & 255;       // H/4 = 256 float4 per row
  const float4 val = ((const float4*)((which ? v : u) + (size_t)b * H_))[h4];
  ((float4*)out)[t] = val;
}

// ---------------------------------------------------------------- launch

extern "C" void kernel_launch(void* const* d_in, const int* in_sizes, int n_in,
                              void* d_out, int out_size, void* d_ws, size_t ws_size,
                              hipStream_t stream) {
  const float* dns   = (const float*)d_in[0];
  const float* img   = (const float*)d_in[1];
  const float* Wi1   = (const float*)d_in[4];
  const float* watt1 = (const float*)d_in[5];
  const float* Wd2   = (const float*)d_in[7];
  const float* watt2 = (const float*)d_in[10];
  float* out = (float*)d_out;   // fp32 output (reference returns float32)

  float* ws = (float*)d_ws;
  float* sPartD = ws;                  // 16384*8 = 131072
  float* sPartB = ws + 131072;         // 6272*8  =  50176
  float* q      = ws + 181248;         // 16384
  float* p      = ws + 197632;         // 6272
  float* uPart  = ws + 203904;         // 16*32768 = 524288
  float* vPart  = ws + 728192;         // 4*32768  = 131072
  float* u      = ws + 859264;         // 32768
  float* v      = ws + 892032;         // 32768
  bh* dnsB = (bh*)(ws + 924800);       // 16,777,216 bf16 (= 8,388,608 floats)
  bh* imgB = (bh*)(ws + 9313408);      //  6,422,528 bf16 (= 3,211,264 floats)
  bh* wd2B = (bh*)(ws + 12524672);     //  1,048,576 bf16 (=   524,288 floats)
  bh* wi1B = (bh*)(ws + 13048960);     //  1,048,576 bf16 -> total 13,573,248 floats (~54.3 MB)

  convert_kernel<<<2048, 256, 0, stream>>>(dns, img, Wd2, Wi1, dnsB, imgB, wd2B, wi1B);
  score_gemm_kernel<<<dim3(8, 128 + 49), 256, 0, stream>>>(
      dnsB, imgB, wd2B, wi1B, watt1, watt2, sPartD, sPartB);
  softmax_kernel<<<B_, 512, 0, stream>>>(sPartD, sPartB, q, p);
  wsum_kernel<<<dim3(B_, 20), 256, 0, stream>>>(dns, img, q, p, uPart, vPart);
  combine_kernel<<<B_, 256, 0, stream>>>(uPart, vPart, u, v);
  bcast_kernel<<<32768, 256, 0, stream>>>(u, v, out);
}

// Round 2
// 323.880 us; speedup vs baseline: 1.0531x; 1.0216x over previous
//
#include <hip/hip_runtime.h>
#include <hip/hip_bf16.h>
#include <stdint.h>

typedef __bf16 bh;
typedef __bf16 bf16x8 __attribute__((ext_vector_type(8)));
typedef float f32x4 __attribute__((ext_vector_type(4)));

#define B_  32
#define S_  512
#define R_  196
#define H_  1024
#define BH  (B_ * H_)

// ---------------------------------------------------------------- helpers

__device__ __forceinline__ float fast_tanh(float x) {
  x = fminf(10.f, fmaxf(-10.f, x));
  float e = __expf(2.f * x);
  return (e - 1.f) / (e + 1.f);
}

__device__ __forceinline__ bf16x8 cvt8(const float4 a, const float4 b) {
  bf16x8 r;
  r[0] = (bh)a.x; r[1] = (bh)a.y; r[2] = (bh)a.z; r[3] = (bh)a.w;
  r[4] = (bh)b.x; r[5] = (bh)b.y; r[6] = (bh)b.z; r[7] = (bh)b.w;
  return r;
}

// async global->LDS, 16B per lane. LDS dest = wave-uniform base + lane*16;
// global src is per-lane (this is how we pre-swizzle). size must be literal.
__device__ __forceinline__ void gload_lds16(const bh* g, bh* l) {
  __builtin_amdgcn_global_load_lds(
      (__attribute__((address_space(1))) void*)g,
      (__attribute__((address_space(3))) void*)l,
      16, 0, 0);
}

// ---------------------------------------------------------------- kernel 0
// One-shot fp32 -> bf16 conversion of dns, img, Wd2, Wi1 (row-major kept).
#define G_DNS 2097152   // 32*512*1024/8
#define G_IMG 802816    // 32*196*1024/8
#define G_W   131072    // 1024*1024/8
#define G_TOT (G_DNS + G_IMG + 2 * G_W)

__global__ __launch_bounds__(256)
void convert_kernel(const float* __restrict__ dns, const float* __restrict__ img,
                    const float* __restrict__ Wd2, const float* __restrict__ Wi1,
                    bh* __restrict__ dnsB, bh* __restrict__ imgB,
                    bh* __restrict__ wd2B, bh* __restrict__ wi1B) {
  for (int g = blockIdx.x * 256 + threadIdx.x; g < G_TOT; g += gridDim.x * 256) {
    const float* src; bh* dst; int off;
    if (g < G_DNS)                    { src = dns; dst = dnsB; off = g; }
    else if (g < G_DNS + G_IMG)       { src = img; dst = imgB; off = g - G_DNS; }
    else if (g < G_DNS + G_IMG + G_W) { src = Wd2; dst = wd2B; off = g - G_DNS - G_IMG; }
    else                              { src = Wi1; dst = wi1B; off = g - G_DNS - G_IMG - G_W; }
    float4 a = ((const float4*)src)[(size_t)off * 2];
    float4 b = ((const float4*)src)[(size_t)off * 2 + 1];
    ((bf16x8*)dst)[off] = cvt8(a, b);
  }
}

// ---------------------------------------------------------------- kernel 1
// Fused GEMM + tanh + weighted-reduce, bf16 inputs.
// 128x128 tile, BK=32, 4 waves of 64x64, 16x16x32 MFMA.
// New this round:
//  - double-buffered LDS + prefetch of tile kt+1 before compute of kt
//    (T3 "minimum 2-phase": one __syncthreads per K-step, load latency
//    hides under ds_read+MFMA).
//  - bank-conflict-free ds_read: LDS segment swizzled by row&2, applied as
//    pre-swizzled GLOBAL source (linear LDS dest, rule 21) + same XOR on read.
//  - bijective XCD-chunk remap: 1416 blocks = 8 XCDs x 177; each XCD gets a
//    contiguous my-range so the 8 ny-blocks of an A-tile share one L2.

__global__ __launch_bounds__(256, 3)
void score_gemm_kernel(const bh* __restrict__ dnsB, const bh* __restrict__ imgB,
                       const bh* __restrict__ Wd2B, const bh* __restrict__ Wi1B,
                       const float* __restrict__ watt1, const float* __restrict__ watt2,
                       float* __restrict__ sPartD, float* __restrict__ sPartB) {
  __shared__ __align__(16) bh As[2][128 * 32];
  __shared__ __align__(16) bh Bs[2][128 * 32];
  __shared__ float sred[128];

  const int tid = threadIdx.x;
  const int wave = tid >> 6, lane = tid & 63;

  // XCD-aware bijective remap (nwg = 1416 = 8*177)
  const int d = blockIdx.x;
  const int k = (d & 7) * 177 + (d >> 3);
  const int my = k >> 3, ny = k & 7;

  const bh* X; const bh* W; const float* w; float* sp; int m0;
  if (my < 128) { X = dnsB; W = Wd2B; w = watt2 + H_; sp = sPartD; m0 = my * 128; }
  else          { X = imgB; W = Wi1B; w = watt1 + H_; sp = sPartB; m0 = (my - 128) * 128; }
  const int n0 = ny * 128;

  // staging: wave covers rows wave*32..+31 via 2 instrs of 16 rows each.
  // LDS dest linear: lane l -> element base + 8*l, i.e. (row = +l>>2, seg = l&3).
  // Source segment pre-swizzled: seg_src = (l&3) ^ ((l>>2)&2)  (= seg ^ (row&2)).
  const int srow  = wave * 32 + (lane >> 2);
  const int ssege = (((lane & 3) ^ ((lane >> 2) & 2)) * 8);
  const bh* Ag = X + ((size_t)(m0 + srow) * H_ + ssege);
  const bh* Bg = W + ((size_t)(n0 + srow) * H_ + ssege);
  const int lw = wave * 32 * 32;   // wave-uniform LDS element base

  const int wm = wave >> 1, wn = wave & 1;
  const int col = lane & 15, quad = lane >> 4;
  // read-side swizzle: segment = quad ^ (row&2), row&2 == col&2 here
  const int qx8 = ((quad ^ (col & 2)) * 8);

  f32x4 acc[4][4] = {};

  // prologue: stage tile 0 into buf 0
  {
    gload_lds16(Ag,            &As[0][lw]);
    gload_lds16(Ag + 16 * H_,  &As[0][lw + 16 * 32]);
    gload_lds16(Bg,            &Bs[0][lw]);
    gload_lds16(Bg + 16 * H_,  &Bs[0][lw + 16 * 32]);
  }
  __syncthreads();   // vmcnt(0) drain: tile 0 resident

  for (int kt = 0; kt < 32; ++kt) {
    const int cur = kt & 1;
    if (kt + 1 < 32) {       // prefetch next tile into the other buffer
      const int ko = (kt + 1) * 32;
      gload_lds16(Ag + ko,            &As[cur ^ 1][lw]);
      gload_lds16(Ag + ko + 16 * H_,  &As[cur ^ 1][lw + 16 * 32]);
      gload_lds16(Bg + ko,            &Bs[cur ^ 1][lw]);
      gload_lds16(Bg + ko + 16 * H_,  &Bs[cur ^ 1][lw + 16 * 32]);
    }

    bf16x8 af[4], bfr[4];
#pragma unroll
    for (int mi = 0; mi < 4; ++mi)
      af[mi] = *(const bf16x8*)(&As[cur][(wm * 64 + mi * 16 + col) * 32 + qx8]);
#pragma unroll
    for (int ni = 0; ni < 4; ++ni)
      bfr[ni] = *(const bf16x8*)(&Bs[cur][(wn * 64 + ni * 16 + col) * 32 + qx8]);

#pragma unroll
    for (int mi = 0; mi < 4; ++mi)
#pragma unroll
      for (int ni = 0; ni < 4; ++ni)
        acc[mi][ni] = __builtin_amdgcn_mfma_f32_16x16x32_bf16(af[mi], bfr[ni], acc[mi][ni], 0, 0, 0);

    __syncthreads();   // vmcnt(0): prefetch landed; lgkm: reads of cur done
  }

  // epilogue: tanh -> *w[o] -> reduce over this block's 128 o-columns.
  // C/D layout (verified m89): col = lane&15, row = quad*4 + reg.
  float wv[4];
#pragma unroll
  for (int ni = 0; ni < 4; ++ni) wv[ni] = w[n0 + wn * 64 + ni * 16 + col];

  float ppv[4][4];
#pragma unroll
  for (int mi = 0; mi < 4; ++mi) {
#pragma unroll
    for (int reg = 0; reg < 4; ++reg) {
      float pp = 0.f;
#pragma unroll
      for (int ni = 0; ni < 4; ++ni) pp += fast_tanh(acc[mi][ni][reg]) * wv[ni];
      pp += __shfl_xor(pp, 1);
      pp += __shfl_xor(pp, 2);
      pp += __shfl_xor(pp, 4);
      pp += __shfl_xor(pp, 8);
      ppv[mi][reg] = pp;   // valid where col==0
    }
  }

  if (wn == 0 && col == 0) {
#pragma unroll
    for (int mi = 0; mi < 4; ++mi)
#pragma unroll
      for (int reg = 0; reg < 4; ++reg)
        sred[wm * 64 + mi * 16 + quad * 4 + reg] = ppv[mi][reg];
  }
  __syncthreads();
  if (wn == 1 && col == 0) {
#pragma unroll
    for (int mi = 0; mi < 4; ++mi)
#pragma unroll
      for (int reg = 0; reg < 4; ++reg) {
        int ml = wm * 64 + mi * 16 + quad * 4 + reg;
        sp[(size_t)(m0 + ml) * 8 + ny] = sred[ml] + ppv[mi][reg];
      }
  }
}

// ---------------------------------------------------------------- kernel 2
// Fused softmax + weighted sum (removes the standalone softmax kernel).
// Each block recomputes its batch's softmax reduction from L2-hot sPart
// (16KB dns / 6KB img redundant reads), then does its chunk's weighted sum.
//   zc<16 : uPart[zc*BH + b*H + h] = sum_{j in [zc*32, +32)} q[b,j]*dns[b,j,h]
//   zc>=16: vPart[(zc-16)*BH + b*H + h] = sum_{r in [(zc-16)*49, +49)} p[b,r]*img[b,r,h]
__global__ __launch_bounds__(256)
void wsum_kernel(const float* __restrict__ dns, const float* __restrict__ img,
                 const float* __restrict__ sPartD, const float* __restrict__ sPartB,
                 float* __restrict__ uPart, float* __restrict__ vPart) {
  __shared__ float red[4];
  __shared__ float es[512];
  const int b = blockIdx.x, tid = threadIdx.x, zc = blockIdx.y;
  const int wave = tid >> 6, lane = tid & 63;
  const int h = tid * 4;

  if (zc < 16) {
    // softmax over 512 dns logits (rows tid and tid+256)
    const float4* p4 = (const float4*)(sPartD + (size_t)b * S_ * 8);
    float4 a0 = p4[tid * 2],        a1 = p4[tid * 2 + 1];
    float4 c0 = p4[(tid + 256) * 2], c1 = p4[(tid + 256) * 2 + 1];
    float x0 = a0.x + a0.y + a0.z + a0.w + a1.x + a1.y + a1.z + a1.w;
    float x1 = c0.x + c0.y + c0.z + c0.w + c1.x + c1.y + c1.z + c1.w;
    float m = fmaxf(x0, x1);
#pragma unroll
    for (int msk = 32; msk; msk >>= 1) m = fmaxf(m, __shfl_xor(m, msk));
    if (!lane) red[wave] = m;
    __syncthreads();
    float bm = fmaxf(fmaxf(red[0], red[1]), fmaxf(red[2], red[3]));
    __syncthreads();
    float e0 = __expf(x0 - bm), e1 = __expf(x1 - bm);
    es[tid] = e0; es[tid + 256] = e1;
    float s = e0 + e1;
#pragma unroll
    for (int msk = 32; msk; msk >>= 1) s += __shfl_xor(s, msk);
    if (!lane) red[wave] = s;
    __syncthreads();
    const float inv = 1.f / (red[0] + red[1] + red[2] + red[3]);

    const int j0 = zc * 32;
    const float* Xb = dns + ((size_t)(b * S_ + j0) * H_ + h);
    float4 a = {0.f, 0.f, 0.f, 0.f};
#pragma unroll
    for (int jj = 0; jj < 32; ++jj) {
      float4 xv = *(const float4*)(Xb + (size_t)jj * H_);
      float qv = es[j0 + jj] * inv;
      a.x += qv * xv.x; a.y += qv * xv.y; a.z += qv * xv.z; a.w += qv * xv.w;
    }
    *(float4*)(uPart + (size_t)zc * BH + (size_t)b * H_ + h) = a;
  } else {
    // softmax over 196 img logits
    const float4* p4 = (const float4*)(sPartB + (size_t)b * R_ * 8);
    float x = -3.0e38f;
    if (tid < R_) {
      float4 a0 = p4[tid * 2], a1 = p4[tid * 2 + 1];
      x = a0.x + a0.y + a0.z + a0.w + a1.x + a1.y + a1.z + a1.w;
    }
    float m = x;
#pragma unroll
    for (int msk = 32; msk; msk >>= 1) m = fmaxf(m, __shfl_xor(m, msk));
    if (!lane) red[wave] = m;
    __syncthreads();
    float bm = fmaxf(fmaxf(red[0], red[1]), fmaxf(red[2], red[3]));
    __syncthreads();
    float e = (tid < R_) ? __expf(x - bm) : 0.f;
    es[tid] = e;
    float s = e;
#pragma unroll
    for (int msk = 32; msk; msk >>= 1) s += __shfl_xor(s, msk);
    if (!lane) red[wave] = s;
    __syncthreads();
    const float inv = 1.f / (red[0] + red[1] + red[2] + red[3]);

    const int j0 = (zc - 16) * 49;
    const float* Xb = img + ((size_t)(b * R_ + j0) * H_ + h);
    float4 a = {0.f, 0.f, 0.f, 0.f};
#pragma unroll
    for (int jj = 0; jj < 49; ++jj) {
      float4 xv = *(const float4*)(Xb + (size_t)jj * H_);
      float qv = es[j0 + jj] * inv;
      a.x += qv * xv.x; a.y += qv * xv.y; a.z += qv * xv.z; a.w += qv * xv.w;
    }
    *(float4*)(vPart + (size_t)(zc - 16) * BH + (size_t)b * H_ + h) = a;
  }
}

// ---------------------------------------------------------------- kernel 3
// Fused combine + broadcast (removes the standalone combine kernel).
// grid 512: block = (b, s-chunk of 32). Each thread re-sums the L2-hot
// partials for its h4 (16+4 float4 loads), then writes 32 rows of both
// output tensors. out0 = att_dns (from u), out1 = att_img (from v).
__global__ __launch_bounds__(256)
void bcast_kernel(const float* __restrict__ uPart, const float* __restrict__ vPart,
                  float* __restrict__ out) {
  const int id = blockIdx.x;       // 0..511
  const int b = id >> 4, sc = id & 15;
  const int t = threadIdx.x;       // h4 index (H/4 = 256)

  float4 u4 = {0.f, 0.f, 0.f, 0.f};
#pragma unroll
  for (int c = 0; c < 16; ++c) {
    float4 s = ((const float4*)(uPart + (size_t)c * BH + (size_t)b * H_))[t];
    u4.x += s.x; u4.y += s.y; u4.z += s.z; u4.w += s.w;
  }
  float4 v4 = {0.f, 0.f, 0.f, 0.f};
#pragma unroll
  for (int c = 0; c < 4; ++c) {
    float4 s = ((const float4*)(vPart + (size_t)c * BH + (size_t)b * H_))[t];
    v4.x += s.x; v4.y += s.y; v4.z += s.z; v4.w += s.w;
  }

  const int PER4 = B_ * S_ * H_ / 4;   // 4,194,304
  float4* o0 = (float4*)out + ((size_t)(b * S_ + sc * 32)) * 256 + t;
  float4* o1 = o0 + PER4;
#pragma unroll
  for (int s = 0; s < 32; ++s) { o0[(size_t)s * 256] = u4; o1[(size_t)s * 256] = v4; }
}

// ---------------------------------------------------------------- launch

extern "C" void kernel_launch(void* const* d_in, const int* in_sizes, int n_in,
                              void* d_out, int out_size, void* d_ws, size_t ws_size,
                              hipStream_t stream) {
  const float* dns   = (const float*)d_in[0];
  const float* img   = (const float*)d_in[1];
  const float* Wi1   = (const float*)d_in[4];
  const float* watt1 = (const float*)d_in[5];
  const float* Wd2   = (const float*)d_in[7];
  const float* watt2 = (const float*)d_in[10];
  float* out = (float*)d_out;

  float* ws = (float*)d_ws;
  float* sPartD = ws;                  // 16384*8 = 131072
  float* sPartB = ws + 131072;         //  6272*8 =  50176
  float* uPart  = ws + 181248;         // 16*32768 = 524288
  float* vPart  = ws + 705536;         //  4*32768 = 131072
  bh* dnsB = (bh*)(ws + 836608);       // 16,777,216 bf16 = 8,388,608 floats
  bh* imgB = (bh*)(ws + 9225216);      //  6,422,528 bf16 = 3,211,264 floats
  bh* wd2B = (bh*)(ws + 12436480);     //  1,048,576 bf16 =   524,288 floats
  bh* wi1B = (bh*)(ws + 12960768);     //  -> total 13,485,056 floats (~53.9 MB)

  convert_kernel<<<2048, 256, 0, stream>>>(dns, img, Wd2, Wi1, dnsB, imgB, wd2B, wi1B);
  score_gemm_kernel<<<1416, 256, 0, stream>>>(
      dnsB, imgB, wd2B, wi1B, watt1, watt2, sPartD, sPartB);
  wsum_kernel<<<dim3(B_, 20), 256, 0, stream>>>(dns, img, sPartD, sPartB, uPart, vPart);
  bcast_kernel<<<512, 256, 0, stream>>>(uPart, vPart, out);
}

// Round 3
// 323.545 us; speedup vs baseline: 1.0542x; 1.0010x over previous
//
#include <hip/hip_runtime.h>
#include <hip/hip_bf16.h>
#include <stdint.h>

typedef __bf16 bh;
typedef __bf16 bf16x8 __attribute__((ext_vector_type(8)));
typedef float f32x4 __attribute__((ext_vector_type(4)));

#define B_  32
#define S_  512
#define R_  196
#define H_  1024
#define BH  (B_ * H_)

// ---------------------------------------------------------------- helpers

__device__ __forceinline__ float fast_tanh(float x) {
  x = fminf(10.f, fmaxf(-10.f, x));
  float e = __expf(2.f * x);
  return (e - 1.f) / (e + 1.f);
}

__device__ __forceinline__ bf16x8 cvt8(const float4 a, const float4 b) {
  bf16x8 r;
  r[0] = (bh)a.x; r[1] = (bh)a.y; r[2] = (bh)a.z; r[3] = (bh)a.w;
  r[4] = (bh)b.x; r[5] = (bh)b.y; r[6] = (bh)b.z; r[7] = (bh)b.w;
  return r;
}

// async global->LDS, 16B per lane. LDS dest = wave-uniform base + lane*16;
// global src is per-lane (used for pre-swizzling). size must be a literal.
__device__ __forceinline__ void gload_lds16(const bh* g, bh* l) {
  __builtin_amdgcn_global_load_lds(
      (__attribute__((address_space(1))) void*)g,
      (__attribute__((address_space(3))) void*)l,
      16, 0, 0);
}

// ---------------------------------------------------------------- kernel 0
// One-shot fp32 -> bf16 conversion of dns, img, Wd2, Wi1 (row-major kept).
#define G_DNS 2097152   // 32*512*1024/8
#define G_IMG 802816    // 32*196*1024/8
#define G_W   131072    // 1024*1024/8
#define G_TOT (G_DNS + G_IMG + 2 * G_W)

__global__ __launch_bounds__(256)
void convert_kernel(const float* __restrict__ dns, const float* __restrict__ img,
                    const float* __restrict__ Wd2, const float* __restrict__ Wi1,
                    bh* __restrict__ dnsB, bh* __restrict__ imgB,
                    bh* __restrict__ wd2B, bh* __restrict__ wi1B) {
  for (int g = blockIdx.x * 256 + threadIdx.x; g < G_TOT; g += gridDim.x * 256) {
    const float* src; bh* dst; int off;
    if (g < G_DNS)                    { src = dns; dst = dnsB; off = g; }
    else if (g < G_DNS + G_IMG)       { src = img; dst = imgB; off = g - G_DNS; }
    else if (g < G_DNS + G_IMG + G_W) { src = Wd2; dst = wd2B; off = g - G_DNS - G_IMG; }
    else                              { src = Wi1; dst = wi1B; off = g - G_DNS - G_IMG - G_W; }
    float4 a = ((const float4*)src)[(size_t)off * 2];
    float4 b = ((const float4*)src)[(size_t)off * 2 + 1];
    ((bf16x8*)dst)[off] = cvt8(a, b);
  }
}

// ---------------------------------------------------------------- kernel 1
// Fused GEMM + tanh + weighted-reduce, bf16 inputs.
// 128x128 tile, BK=32, 4 waves of 64x64, 16x16x32 MFMA, double-buffered
// global_load_lds staging, XCD-bijective block remap.
// This round: full 2-bit LDS XOR-swizzle (seg ^= (row>>1)&3) applied as
// pre-swizzled global source + same XOR on ds_read -> 2 lanes/bank (free),
// and occupancy 3->4 blocks/CU.

__global__ __launch_bounds__(256, 4)
void score_gemm_kernel(const bh* __restrict__ dnsB, const bh* __restrict__ imgB,
                       const bh* __restrict__ Wd2B, const bh* __restrict__ Wi1B,
                       const float* __restrict__ watt1, const float* __restrict__ watt2,
                       float* __restrict__ sPartD, float* __restrict__ sPartB) {
  __shared__ __align__(16) bh As[2][128 * 32];
  __shared__ __align__(16) bh Bs[2][128 * 32];
  __shared__ float sred[128];

  const int tid = threadIdx.x;
  const int wave = tid >> 6, lane = tid & 63;

  // XCD-aware bijective remap (nwg = 1416 = 8*177)
  const int d = blockIdx.x;
  const int k = (d & 7) * 177 + (d >> 3);
  const int my = k >> 3, ny = k & 7;

  const bh* X; const bh* W; const float* w; float* sp; int m0;
  if (my < 128) { X = dnsB; W = Wd2B; w = watt2 + H_; sp = sPartD; m0 = my * 128; }
  else          { X = imgB; W = Wi1B; w = watt1 + H_; sp = sPartB; m0 = (my - 128) * 128; }
  const int n0 = ny * 128;

  // staging: wave covers rows wave*32..+31 via 2 instrs of 16 rows each.
  // LDS dest linear: lane l -> (row += l>>2, seg = l&3).
  // Swizzle: LDS slot (r, s) holds global (r, s ^ ((r>>1)&3)).
  // Source seg for lane l: (l&3) ^ ((l>>3)&3)  (row bits 1..2 = (l>>3)&3;
  // the +16-row second instr and wave*32 base don't touch those bits).
  const int srow  = wave * 32 + (lane >> 2);
  const int ssege = (((lane & 3) ^ ((lane >> 3) & 3)) * 8);
  const bh* Ag = X + ((size_t)(m0 + srow) * H_ + ssege);
  const bh* Bg = W + ((size_t)(n0 + srow) * H_ + ssege);
  const int lw = wave * 32 * 32;   // wave-uniform LDS element base

  const int wm = wave >> 1, wn = wave & 1;
  const int col = lane & 15, quad = lane >> 4;
  // read-side swizzle: row = (64|16)-aligned base + col -> (row>>1)&3 = (col>>1)&3
  const int qx8 = ((quad ^ ((col >> 1) & 3)) * 8);

  f32x4 acc[4][4] = {};

  // prologue: stage tile 0 into buf 0
  gload_lds16(Ag,            &As[0][lw]);
  gload_lds16(Ag + 16 * H_,  &As[0][lw + 16 * 32]);
  gload_lds16(Bg,            &Bs[0][lw]);
  gload_lds16(Bg + 16 * H_,  &Bs[0][lw + 16 * 32]);
  __syncthreads();

  for (int kt = 0; kt < 32; ++kt) {
    const int cur = kt & 1;
    if (kt + 1 < 32) {       // prefetch next tile into the other buffer
      const int ko = (kt + 1) * 32;
      gload_lds16(Ag + ko,            &As[cur ^ 1][lw]);
      gload_lds16(Ag + ko + 16 * H_,  &As[cur ^ 1][lw + 16 * 32]);
      gload_lds16(Bg + ko,            &Bs[cur ^ 1][lw]);
      gload_lds16(Bg + ko + 16 * H_,  &Bs[cur ^ 1][lw + 16 * 32]);
    }

    bf16x8 af[4], bfr[4];
#pragma unroll
    for (int mi = 0; mi < 4; ++mi)
      af[mi] = *(const bf16x8*)(&As[cur][(wm * 64 + mi * 16 + col) * 32 + qx8]);
#pragma unroll
    for (int ni = 0; ni < 4; ++ni)
      bfr[ni] = *(const bf16x8*)(&Bs[cur][(wn * 64 + ni * 16 + col) * 32 + qx8]);

#pragma unroll
    for (int mi = 0; mi < 4; ++mi)
#pragma unroll
      for (int ni = 0; ni < 4; ++ni)
        acc[mi][ni] = __builtin_amdgcn_mfma_f32_16x16x32_bf16(af[mi], bfr[ni], acc[mi][ni], 0, 0, 0);

    __syncthreads();   // prefetch landed; reads of cur done
  }

  // epilogue: tanh -> *w[o] -> reduce over this block's 128 o-columns.
  // C/D layout (verified m89): col = lane&15, row = quad*4 + reg.
  float wv[4];
#pragma unroll
  for (int ni = 0; ni < 4; ++ni) wv[ni] = w[n0 + wn * 64 + ni * 16 + col];

  float ppv[4][4];
#pragma unroll
  for (int mi = 0; mi < 4; ++mi) {
#pragma unroll
    for (int reg = 0; reg < 4; ++reg) {
      float pp = 0.f;
#pragma unroll
      for (int ni = 0; ni < 4; ++ni) pp += fast_tanh(acc[mi][ni][reg]) * wv[ni];
      pp += __shfl_xor(pp, 1);
      pp += __shfl_xor(pp, 2);
      pp += __shfl_xor(pp, 4);
      pp += __shfl_xor(pp, 8);
      ppv[mi][reg] = pp;   // valid where col==0
    }
  }

  if (wn == 0 && col == 0) {
#pragma unroll
    for (int mi = 0; mi < 4; ++mi)
#pragma unroll
      for (int reg = 0; reg < 4; ++reg)
        sred[wm * 64 + mi * 16 + quad * 4 + reg] = ppv[mi][reg];
  }
  __syncthreads();
  if (wn == 1 && col == 0) {
#pragma unroll
    for (int mi = 0; mi < 4; ++mi)
#pragma unroll
      for (int reg = 0; reg < 4; ++reg) {
        int ml = wm * 64 + mi * 16 + quad * 4 + reg;
        sp[(size_t)(m0 + ml) * 8 + ny] = sred[ml] + ppv[mi][reg];
      }
  }
}

// ---------------------------------------------------------------- kernel 2
// Fully fused softmax + weighted-sum + broadcast-write.
// grid (B, 16): block (b, hc) owns h-slice [hc*64, +64).
// Phase 1: recompute both softmaxes for batch b from L2-hot sPart.
// Phase 2: thread t = (jg = t>>4, h4 = t&15) accumulates u/v over
//          j = jg + 16*it; shuffle+LDS reduce across the 16 jg groups.
// Phase 3: broadcast-write 512 rows x 16 float4 of BOTH outputs.
__global__ __launch_bounds__(256)
void wsum_bcast_kernel(const float* __restrict__ dns, const float* __restrict__ img,
                       const float* __restrict__ sPartD, const float* __restrict__ sPartB,
                       float* __restrict__ out) {
  __shared__ float red[4];
  __shared__ float esd[512];
  __shared__ float esi[196];
  __shared__ float4 aru[4][16];
  __shared__ float4 arv[4][16];
  __shared__ float4 su[16], sv[16];

  const int b = blockIdx.x, hc = blockIdx.y;
  const int tid = threadIdx.x, wave = tid >> 6, lane = tid & 63;
  float inv_d, inv_i;

  {  // softmax over 512 dns logits (rows tid and tid+256)
    const float4* p4 = (const float4*)(sPartD + (size_t)b * S_ * 8);
    float4 a0 = p4[tid * 2],         a1 = p4[tid * 2 + 1];
    float4 c0 = p4[(tid + 256) * 2], c1 = p4[(tid + 256) * 2 + 1];
    float x0 = a0.x + a0.y + a0.z + a0.w + a1.x + a1.y + a1.z + a1.w;
    float x1 = c0.x + c0.y + c0.z + c0.w + c1.x + c1.y + c1.z + c1.w;
    float m = fmaxf(x0, x1);
#pragma unroll
    for (int msk = 32; msk; msk >>= 1) m = fmaxf(m, __shfl_xor(m, msk));
    if (!lane) red[wave] = m;
    __syncthreads();
    float bm = fmaxf(fmaxf(red[0], red[1]), fmaxf(red[2], red[3]));
    __syncthreads();
    float e0 = __expf(x0 - bm), e1 = __expf(x1 - bm);
    esd[tid] = e0; esd[tid + 256] = e1;
    float s = e0 + e1;
#pragma unroll
    for (int msk = 32; msk; msk >>= 1) s += __shfl_xor(s, msk);
    if (!lane) red[wave] = s;
    __syncthreads();
    inv_d = 1.f / (red[0] + red[1] + red[2] + red[3]);
    __syncthreads();
  }
  {  // softmax over 196 img logits
    float x = -3.0e38f;
    if (tid < R_) {
      const float4* p4 = (const float4*)(sPartB + (size_t)b * R_ * 8);
      float4 a0 = p4[tid * 2], a1 = p4[tid * 2 + 1];
      x = a0.x + a0.y + a0.z + a0.w + a1.x + a1.y + a1.z + a1.w;
    }
    float m = x;
#pragma unroll
    for (int msk = 32; msk; msk >>= 1) m = fmaxf(m, __shfl_xor(m, msk));
    if (!lane) red[wave] = m;
    __syncthreads();
    float bm = fmaxf(fmaxf(red[0], red[1]), fmaxf(red[2], red[3]));
    __syncthreads();
    float e = (tid < R_) ? __expf(x - bm) : 0.f;
    if (tid < R_) esi[tid] = e;
    float s = e;
#pragma unroll
    for (int msk = 32; msk; msk >>= 1) s += __shfl_xor(s, msk);
    if (!lane) red[wave] = s;
    __syncthreads();
    inv_i = 1.f / (red[0] + red[1] + red[2] + red[3]);
    __syncthreads();   // esd/esi fully written before phase 2 reads
  }

  // ---- phase 2: partial weighted sums for this h-slice
  const int h4 = tid & 15, jg = tid >> 4;
  const float* db = dns + (size_t)b * S_ * H_ + hc * 64 + h4 * 4;
  float4 ua = {0.f, 0.f, 0.f, 0.f};
#pragma unroll
  for (int it = 0; it < 32; ++it) {
    const int j = jg + it * 16;
    float4 xv = *(const float4*)(db + (size_t)j * H_);
    float qv = esd[j];
    ua.x += qv * xv.x; ua.y += qv * xv.y; ua.z += qv * xv.z; ua.w += qv * xv.w;
  }
  const float* ib = img + (size_t)b * R_ * H_ + hc * 64 + h4 * 4;
  float4 va = {0.f, 0.f, 0.f, 0.f};
#pragma unroll
  for (int it = 0; it < 13; ++it) {
    const int j = jg + it * 16;
    if (j < R_) {
      float4 xv = *(const float4*)(ib + (size_t)j * H_);
      float pv = esi[j];
      va.x += pv * xv.x; va.y += pv * xv.y; va.z += pv * xv.z; va.w += pv * xv.w;
    }
  }
  // reduce the 4 jg-groups within each wave (lane ^ 16, ^ 32)
#pragma unroll
  for (int msk = 16; msk <= 32; msk <<= 1) {
    ua.x += __shfl_xor(ua.x, msk); ua.y += __shfl_xor(ua.y, msk);
    ua.z += __shfl_xor(ua.z, msk); ua.w += __shfl_xor(ua.w, msk);
    va.x += __shfl_xor(va.x, msk); va.y += __shfl_xor(va.y, msk);
    va.z += __shfl_xor(va.z, msk); va.w += __shfl_xor(va.w, msk);
  }
  if (lane < 16) { aru[wave][lane] = ua; arv[wave][lane] = va; }
  __syncthreads();
  if (tid < 16) {
    float4 s0 = aru[0][tid], s1 = aru[1][tid], s2 = aru[2][tid], s3 = aru[3][tid];
    float4 r;
    r.x = (s0.x + s1.x + s2.x + s3.x) * inv_d;
    r.y = (s0.y + s1.y + s2.y + s3.y) * inv_d;
    r.z = (s0.z + s1.z + s2.z + s3.z) * inv_d;
    r.w = (s0.w + s1.w + s2.w + s3.w) * inv_d;
    su[tid] = r;
    s0 = arv[0][tid]; s1 = arv[1][tid]; s2 = arv[2][tid]; s3 = arv[3][tid];
    r.x = (s0.x + s1.x + s2.x + s3.x) * inv_i;
    r.y = (s0.y + s1.y + s2.y + s3.y) * inv_i;
    r.z = (s0.z + s1.z + s2.z + s3.z) * inv_i;
    r.w = (s0.w + s1.w + s2.w + s3.w) * inv_i;
    sv[tid] = r;
  }
  __syncthreads();

  // ---- phase 3: broadcast write. thread covers rows jg + 16*s, col h4.
  const int PER4 = B_ * S_ * H_ / 4;   // 4,194,304
  const float4 u4 = su[h4], v4 = sv[h4];
  float4* o0 = (float4*)out + ((size_t)b * S_ + jg) * 256 + hc * 16 + h4;
  float4* o1 = o0 + PER4;
#pragma unroll
  for (int s = 0; s < 32; ++s) {
    o0[(size_t)s * 16 * 256] = u4;
    o1[(size_t)s * 16 * 256] = v4;
  }
}

// ---------------------------------------------------------------- launch

extern "C" void kernel_launch(void* const* d_in, const int* in_sizes, int n_in,
                              void* d_out, int out_size, void* d_ws, size_t ws_size,
                              hipStream_t stream) {
  const float* dns   = (const float*)d_in[0];
  const float* img   = (const float*)d_in[1];
  const float* Wi1   = (const float*)d_in[4];
  const float* watt1 = (const float*)d_in[5];
  const float* Wd2   = (const float*)d_in[7];
  const float* watt2 = (const float*)d_in[10];
  float* out = (float*)d_out;

  float* ws = (float*)d_ws;
  float* sPartD = ws;                  // 16384*8 = 131072 floats
  float* sPartB = ws + 131072;         //  6272*8 =  50176
  bh* dnsB = (bh*)(ws + 181248);       // 16,777,216 bf16 = 8,388,608 floats
  bh* imgB = (bh*)(ws + 8569856);      //  6,422,528 bf16 = 3,211,264 floats
  bh* wd2B = (bh*)(ws + 11781120);     //  1,048,576 bf16 =   524,288 floats
  bh* wi1B = (bh*)(ws + 12305408);     //  -> end 12,829,696 floats (~51.3 MB)

  convert_kernel<<<2048, 256, 0, stream>>>(dns, img, Wd2, Wi1, dnsB, imgB, wd2B, wi1B);
  score_gemm_kernel<<<1416, 256, 0, stream>>>(
      dnsB, imgB, wd2B, wi1B, watt1, watt2, sPartD, sPartB);
  wsum_bcast_kernel<<<dim3(B_, 16), 256, 0, stream>>>(dns, img, sPartD, sPartB, out);
}

// Round 4
// 320.116 us; speedup vs baseline: 1.0655x; 1.0107x over previous
//
#include <hip/hip_runtime.h>
#include <hip/hip_bf16.h>
#include <stdint.h>

typedef __bf16 bh;
typedef __bf16 bf16x8 __attribute__((ext_vector_type(8)));
typedef float f32x4 __attribute__((ext_vector_type(4)));

#define B_  32
#define S_  512
#define R_  196
#define H_  1024
#define BH  (B_ * H_)

// ---------------------------------------------------------------- helpers

__device__ __forceinline__ float fast_tanh(float x) {
  x = fminf(10.f, fmaxf(-10.f, x));
  float e = __expf(2.f * x);
  return (e - 1.f) / (e + 1.f);
}

__device__ __forceinline__ bf16x8 cvt8(const float4 a, const float4 b) {
  bf16x8 r;
  r[0] = (bh)a.x; r[1] = (bh)a.y; r[2] = (bh)a.z; r[3] = (bh)a.w;
  r[4] = (bh)b.x; r[5] = (bh)b.y; r[6] = (bh)b.z; r[7] = (bh)b.w;
  return r;
}

// async global->LDS, 16B per lane. LDS dest = wave-uniform base + lane*16;
// global src is per-lane (used for pre-swizzling). size must be a literal.
__device__ __forceinline__ void gload_lds16(const bh* g, bh* l) {
  __builtin_amdgcn_global_load_lds(
      (__attribute__((address_space(1))) void*)g,
      (__attribute__((address_space(3))) void*)l,
      16, 0, 0);
}

// ---------------------------------------------------------------- kernel 0
// One-shot fp32 -> bf16 conversion of dns, img, Wd2, Wi1 (row-major kept).
#define G_DNS 2097152   // 32*512*1024/8
#define G_IMG 802816    // 32*196*1024/8
#define G_W   131072    // 1024*1024/8
#define G_TOT (G_DNS + G_IMG + 2 * G_W)

__global__ __launch_bounds__(256)
void convert_kernel(const float* __restrict__ dns, const float* __restrict__ img,
                    const float* __restrict__ Wd2, const float* __restrict__ Wi1,
                    bh* __restrict__ dnsB, bh* __restrict__ imgB,
                    bh* __restrict__ wd2B, bh* __restrict__ wi1B) {
  for (int g = blockIdx.x * 256 + threadIdx.x; g < G_TOT; g += gridDim.x * 256) {
    const float* src; bh* dst; int off;
    if (g < G_DNS)                    { src = dns; dst = dnsB; off = g; }
    else if (g < G_DNS + G_IMG)       { src = img; dst = imgB; off = g - G_DNS; }
    else if (g < G_DNS + G_IMG + G_W) { src = Wd2; dst = wd2B; off = g - G_DNS - G_IMG; }
    else                              { src = Wi1; dst = wi1B; off = g - G_DNS - G_IMG - G_W; }
    float4 a = ((const float4*)src)[(size_t)off * 2];
    float4 b = ((const float4*)src)[(size_t)off * 2 + 1];
    ((bf16x8*)dst)[off] = cvt8(a, b);
  }
}

// ---------------------------------------------------------------- kernel 1
// Fused GEMM + tanh + weighted-reduce, bf16 inputs.
// 128x128 tile, BK=32, 4 waves of 64x64, 16x16x32 MFMA, 2-bit LDS XOR
// swizzle (pre-swizzled global src + same XOR on read), XCD-bijective remap.
// This round (T3/T4/T5): 2-tile-deep prefetch with counted s_waitcnt
// vmcnt(4) + raw s_barrier (NO vmcnt(0) drain in the main loop) and
// setprio(1) around the MFMA cluster.

__device__ __forceinline__ void frag_load(const bh* Asb, const bh* Bsb,
                                          int abase, int bbase,
                                          bf16x8 af[4], bf16x8 bfr[4]) {
#pragma unroll
  for (int mi = 0; mi < 4; ++mi) af[mi]  = *(const bf16x8*)(Asb + abase + mi * 16 * 32);
#pragma unroll
  for (int ni = 0; ni < 4; ++ni) bfr[ni] = *(const bf16x8*)(Bsb + bbase + ni * 16 * 32);
}

__device__ __forceinline__ void mfma16(const bf16x8 af[4], const bf16x8 bfr[4],
                                       f32x4 acc[4][4]) {
  __builtin_amdgcn_s_setprio(1);
#pragma unroll
  for (int mi = 0; mi < 4; ++mi)
#pragma unroll
    for (int ni = 0; ni < 4; ++ni)
      acc[mi][ni] = __builtin_amdgcn_mfma_f32_16x16x32_bf16(af[mi], bfr[ni], acc[mi][ni], 0, 0, 0);
  __builtin_amdgcn_s_setprio(0);
}

__global__ __launch_bounds__(256, 4)
void score_gemm_kernel(const bh* __restrict__ dnsB, const bh* __restrict__ imgB,
                       const bh* __restrict__ Wd2B, const bh* __restrict__ Wi1B,
                       const float* __restrict__ watt1, const float* __restrict__ watt2,
                       float* __restrict__ sPartD, float* __restrict__ sPartB) {
  __shared__ __align__(16) bh As[2][128 * 32];
  __shared__ __align__(16) bh Bs[2][128 * 32];
  __shared__ float sred[128];

  const int tid = threadIdx.x;
  const int wave = tid >> 6, lane = tid & 63;

  // XCD-aware bijective remap (nwg = 1416 = 8*177)
  const int d = blockIdx.x;
  const int k = (d & 7) * 177 + (d >> 3);
  const int my = k >> 3, ny = k & 7;

  const bh* X; const bh* W; const float* w; float* sp; int m0;
  if (my < 128) { X = dnsB; W = Wd2B; w = watt2 + H_; sp = sPartD; m0 = my * 128; }
  else          { X = imgB; W = Wi1B; w = watt1 + H_; sp = sPartB; m0 = (my - 128) * 128; }
  const int n0 = ny * 128;

  // staging: wave covers rows wave*32..+31 via 2 instrs of 16 rows each.
  // LDS slot (r,s) holds global (r, s ^ ((r>>1)&3)); source seg for lane l:
  // (l&3) ^ ((l>>3)&3).
  const int srow  = wave * 32 + (lane >> 2);
  const int ssege = (((lane & 3) ^ ((lane >> 3) & 3)) * 8);
  const bh* Ag = X + ((size_t)(m0 + srow) * H_ + ssege);
  const bh* Bg = W + ((size_t)(n0 + srow) * H_ + ssege);
  const int lw = wave * 32 * 32;   // wave-uniform LDS element base

  const int wm = wave >> 1, wn = wave & 1;
  const int col = lane & 15, quad = lane >> 4;
  const int qx8 = ((quad ^ ((col >> 1) & 3)) * 8);
  const int abase = (wm * 64 + col) * 32 + qx8;
  const int bbase = (wn * 64 + col) * 32 + qx8;

  f32x4 acc[4][4] = {};

#define STAGE(buf, kt) {                                        \
    const int ko_ = (kt) * 32;                                  \
    gload_lds16(Ag + ko_,           &As[buf][lw]);              \
    gload_lds16(Ag + ko_ + 16 * H_, &As[buf][lw + 16 * 32]);    \
    gload_lds16(Bg + ko_,           &Bs[buf][lw]);              \
    gload_lds16(Bg + ko_ + 16 * H_, &Bs[buf][lw + 16 * 32]); }

  // prologue: tiles 0 and 1 in flight (8 loads), wait oldest 4 -> tile 0 ready
  STAGE(0, 0);
  STAGE(1, 1);
  asm volatile("s_waitcnt vmcnt(4)" ::: "memory");
  __builtin_amdgcn_s_barrier();

  // main loop: t = 0..29. Invariant at top: tile t resident & visible,
  // tile t+1's 4 loads in flight.
  for (int t = 0; t < 30; ++t) {
    const int cur = t & 1;
    bf16x8 af[4], bfr[4];
    frag_load(As[cur], Bs[cur], abase, bbase, af, bfr);
    asm volatile("s_waitcnt lgkmcnt(0)" ::: "memory");
    __builtin_amdgcn_sched_barrier(0);
    __builtin_amdgcn_s_barrier();          // all waves done reading buf[cur]
    STAGE(cur, t + 2);                     // refill freed buffer (async)
    mfma16(af, bfr, acc);                  // overlaps the 8 in-flight loads
    asm volatile("s_waitcnt vmcnt(4)" ::: "memory");   // tile t+1 landed
    __builtin_amdgcn_s_barrier();
  }
  {  // t = 30: no stage (t+2 == 32); drain tile 31 fully at bottom
    bf16x8 af[4], bfr[4];
    frag_load(As[0], Bs[0], abase, bbase, af, bfr);
    mfma16(af, bfr, acc);
    asm volatile("s_waitcnt vmcnt(0)" ::: "memory");
    __builtin_amdgcn_s_barrier();
  }
  {  // t = 31
    bf16x8 af[4], bfr[4];
    frag_load(As[1], Bs[1], abase, bbase, af, bfr);
    mfma16(af, bfr, acc);
  }
#undef STAGE

  // epilogue: tanh -> *w[o] -> reduce over this block's 128 o-columns.
  // C/D layout (verified m89): col = lane&15, row = quad*4 + reg.
  float wv[4];
#pragma unroll
  for (int ni = 0; ni < 4; ++ni) wv[ni] = w[n0 + wn * 64 + ni * 16 + col];

  float ppv[4][4];
#pragma unroll
  for (int mi = 0; mi < 4; ++mi) {
#pragma unroll
    for (int reg = 0; reg < 4; ++reg) {
      float pp = 0.f;
#pragma unroll
      for (int ni = 0; ni < 4; ++ni) pp += fast_tanh(acc[mi][ni][reg]) * wv[ni];
      pp += __shfl_xor(pp, 1);
      pp += __shfl_xor(pp, 2);
      pp += __shfl_xor(pp, 4);
      pp += __shfl_xor(pp, 8);
      ppv[mi][reg] = pp;   // valid where col==0
    }
  }

  if (wn == 0 && col == 0) {
#pragma unroll
    for (int mi = 0; mi < 4; ++mi)
#pragma unroll
      for (int reg = 0; reg < 4; ++reg)
        sred[wm * 64 + mi * 16 + quad * 4 + reg] = ppv[mi][reg];
  }
  __syncthreads();
  if (wn == 1 && col == 0) {
#pragma unroll
    for (int mi = 0; mi < 4; ++mi)
#pragma unroll
      for (int reg = 0; reg < 4; ++reg) {
        int ml = wm * 64 + mi * 16 + quad * 4 + reg;
        sp[(size_t)(m0 + ml) * 8 + ny] = sred[ml] + ppv[mi][reg];
      }
  }
}

// ---------------------------------------------------------------- kernel 2
// Fully fused softmax + weighted-sum + broadcast-write.
// grid (B, 16): block (b, hc) owns h-slice [hc*64, +64).
__global__ __launch_bounds__(256)
void wsum_bcast_kernel(const float* __restrict__ dns, const float* __restrict__ img,
                       const float* __restrict__ sPartD, const float* __restrict__ sPartB,
                       float* __restrict__ out) {
  __shared__ float red[4];
  __shared__ float esd[512];
  __shared__ float esi[196];
  __shared__ float4 aru[4][16];
  __shared__ float4 arv[4][16];
  __shared__ float4 su[16], sv[16];

  const int b = blockIdx.x, hc = blockIdx.y;
  const int tid = threadIdx.x, wave = tid >> 6, lane = tid & 63;
  float inv_d, inv_i;

  {  // softmax over 512 dns logits (rows tid and tid+256)
    const float4* p4 = (const float4*)(sPartD + (size_t)b * S_ * 8);
    float4 a0 = p4[tid * 2],         a1 = p4[tid * 2 + 1];
    float4 c0 = p4[(tid + 256) * 2], c1 = p4[(tid + 256) * 2 + 1];
    float x0 = a0.x + a0.y + a0.z + a0.w + a1.x + a1.y + a1.z + a1.w;
    float x1 = c0.x + c0.y + c0.z + c0.w + c1.x + c1.y + c1.z + c1.w;
    float m = fmaxf(x0, x1);
#pragma unroll
    for (int msk = 32; msk; msk >>= 1) m = fmaxf(m, __shfl_xor(m, msk));
    if (!lane) red[wave] = m;
    __syncthreads();
    float bm = fmaxf(fmaxf(red[0], red[1]), fmaxf(red[2], red[3]));
    __syncthreads();
    float e0 = __expf(x0 - bm), e1 = __expf(x1 - bm);
    esd[tid] = e0; esd[tid + 256] = e1;
    float s = e0 + e1;
#pragma unroll
    for (int msk = 32; msk; msk >>= 1) s += __shfl_xor(s, msk);
    if (!lane) red[wave] = s;
    __syncthreads();
    inv_d = 1.f / (red[0] + red[1] + red[2] + red[3]);
    __syncthreads();
  }
  {  // softmax over 196 img logits
    float x = -3.0e38f;
    if (tid < R_) {
      const float4* p4 = (const float4*)(sPartB + (size_t)b * R_ * 8);
      float4 a0 = p4[tid * 2], a1 = p4[tid * 2 + 1];
      x = a0.x + a0.y + a0.z + a0.w + a1.x + a1.y + a1.z + a1.w;
    }
    float m = x;
#pragma unroll
    for (int msk = 32; msk; msk >>= 1) m = fmaxf(m, __shfl_xor(m, msk));
    if (!lane) red[wave] = m;
    __syncthreads();
    float bm = fmaxf(fmaxf(red[0], red[1]), fmaxf(red[2], red[3]));
    __syncthreads();
    float e = (tid < R_) ? __expf(x - bm) : 0.f;
    if (tid < R_) esi[tid] = e;
    float s = e;
#pragma unroll
    for (int msk = 32; msk; msk >>= 1) s += __shfl_xor(s, msk);
    if (!lane) red[wave] = s;
    __syncthreads();
    inv_i = 1.f / (red[0] + red[1] + red[2] + red[3]);
    __syncthreads();   // esd/esi fully written before phase 2 reads
  }

  // ---- phase 2: partial weighted sums for this h-slice
  const int h4 = tid & 15, jg = tid >> 4;
  const float* db = dns + (size_t)b * S_ * H_ + hc * 64 + h4 * 4;
  float4 ua = {0.f, 0.f, 0.f, 0.f};
#pragma unroll
  for (int it = 0; it < 32; ++it) {
    const int j = jg + it * 16;
    float4 xv = *(const float4*)(db + (size_t)j * H_);
    float qv = esd[j];
    ua.x += qv * xv.x; ua.y += qv * xv.y; ua.z += qv * xv.z; ua.w += qv * xv.w;
  }
  const float* ib = img + (size_t)b * R_ * H_ + hc * 64 + h4 * 4;
  float4 va = {0.f, 0.f, 0.f, 0.f};
#pragma unroll
  for (int it = 0; it < 13; ++it) {
    const int j = jg + it * 16;
    if (j < R_) {
      float4 xv = *(const float4*)(ib + (size_t)j * H_);
      float pv = esi[j];
      va.x += pv * xv.x; va.y += pv * xv.y; va.z += pv * xv.z; va.w += pv * xv.w;
    }
  }
  // reduce the 4 jg-groups within each wave (lane ^ 16, ^ 32)
#pragma unroll
  for (int msk = 16; msk <= 32; msk <<= 1) {
    ua.x += __shfl_xor(ua.x, msk); ua.y += __shfl_xor(ua.y, msk);
    ua.z += __shfl_xor(ua.z, msk); ua.w += __shfl_xor(ua.w, msk);
    va.x += __shfl_xor(va.x, msk); va.y += __shfl_xor(va.y, msk);
    va.z += __shfl_xor(va.z, msk); va.w += __shfl_xor(va.w, msk);
  }
  if (lane < 16) { aru[wave][lane] = ua; arv[wave][lane] = va; }
  __syncthreads();
  if (tid < 16) {
    float4 s0 = aru[0][tid], s1 = aru[1][tid], s2 = aru[2][tid], s3 = aru[3][tid];
    float4 r;
    r.x = (s0.x + s1.x + s2.x + s3.x) * inv_d;
    r.y = (s0.y + s1.y + s2.y + s3.y) * inv_d;
    r.z = (s0.z + s1.z + s2.z + s3.z) * inv_d;
    r.w = (s0.w + s1.w + s2.w + s3.w) * inv_d;
    su[tid] = r;
    s0 = arv[0][tid]; s1 = arv[1][tid]; s2 = arv[2][tid]; s3 = arv[3][tid];
    r.x = (s0.x + s1.x + s2.x + s3.x) * inv_i;
    r.y = (s0.y + s1.y + s2.y + s3.y) * inv_i;
    r.z = (s0.z + s1.z + s2.z + s3.z) * inv_i;
    r.w = (s0.w + s1.w + s2.w + s3.w) * inv_i;
    sv[tid] = r;
  }
  __syncthreads();

  // ---- phase 3: broadcast write. thread covers rows jg + 16*s, col h4.
  const int PER4 = B_ * S_ * H_ / 4;   // 4,194,304
  const float4 u4 = su[h4], v4 = sv[h4];
  float4* o0 = (float4*)out + ((size_t)b * S_ + jg) * 256 + hc * 16 + h4;
  float4* o1 = o0 + PER4;
#pragma unroll
  for (int s = 0; s < 32; ++s) {
    o0[(size_t)s * 16 * 256] = u4;
    o1[(size_t)s * 16 * 256] = v4;
  }
}

// ---------------------------------------------------------------- launch

extern "C" void kernel_launch(void* const* d_in, const int* in_sizes, int n_in,
                              void* d_out, int out_size, void* d_ws, size_t ws_size,
                              hipStream_t stream) {
  const float* dns   = (const float*)d_in[0];
  const float* img   = (const float*)d_in[1];
  const float* Wi1   = (const float*)d_in[4];
  const float* watt1 = (const float*)d_in[5];
  const float* Wd2   = (const float*)d_in[7];
  const float* watt2 = (const float*)d_in[10];
  float* out = (float*)d_out;

  float* ws = (float*)d_ws;
  float* sPartD = ws;                  // 16384*8 = 131072 floats
  float* sPartB = ws + 131072;         //  6272*8 =  50176
  bh* dnsB = (bh*)(ws + 181248);       // 16,777,216 bf16 = 8,388,608 floats
  bh* imgB = (bh*)(ws + 8569856);      //  6,422,528 bf16 = 3,211,264 floats
  bh* wd2B = (bh*)(ws + 11781120);     //  1,048,576 bf16 =   524,288 floats
  bh* wi1B = (bh*)(ws + 12305408);     //  -> end 12,829,696 floats (~51.3 MB)

  convert_kernel<<<2048, 256, 0, stream>>>(dns, img, Wd2, Wi1, dnsB, imgB, wd2B, wi1B);
  score_gemm_kernel<<<1416, 256, 0, stream>>>(
      dnsB, imgB, wd2B, wi1B, watt1, watt2, sPartD, sPartB);
  wsum_bcast_kernel<<<dim3(B_, 16), 256, 0, stream>>>(dns, img, sPartD, sPartB, out);
}